// Round 1
// baseline (185.189 us; speedup 1.0000x reference)
//
#include <hip/hip_runtime.h>
#include <math.h>

// Problem constants (from reference setup_inputs)
#define BB 8
#define CC 192
#define HH 128
#define WW 128
#define TILE_H 16
#define LDS_ROWS (TILE_H + 2)
#define LDS_COLS (WW + 2)   // +2 for zero halo columns

__global__ __launch_bounds__(256) void dynmorph_kernel(
    const float* __restrict__ x,      // [B, C, H, W]
    const float* __restrict__ kern,   // [C, 9]
    const float* __restrict__ gw,     // [C]
    const float* __restrict__ gb,     // [C]
    float* __restrict__ out)          // [B, C, H, W]
{
    __shared__ float s[LDS_ROWS][LDS_COLS];

    const int tid = threadIdx.x;
    const int h0  = blockIdx.x * TILE_H;
    const int c   = blockIdx.y;
    const int b   = blockIdx.z;

    const float* xp = x   + ((size_t)(b * CC + c)) * (HH * WW);
    float*       op = out + ((size_t)(b * CC + c)) * (HH * WW);

    // Zero the side halo columns (zero padding semantics)
    if (tid < LDS_ROWS) {
        s[tid][0]      = 0.0f;
        s[tid][WW + 1] = 0.0f;
    }

    // Stage 18 rows x 128 cols into LDS with float4 loads.
    // lds row lr <-> global row (h0 - 1 + lr); lds col lc <-> global col (lc - 1)
    for (int i = tid; i < LDS_ROWS * (WW / 4); i += 256) {
        const int lr = i >> 5;      // i / 32
        const int vc = i & 31;      // i % 32
        const int g  = h0 - 1 + lr;
        float4 v;
        if (g >= 0 && g < HH) {
            v = *(const float4*)(xp + g * WW + vc * 4);
        } else {
            v = make_float4(0.0f, 0.0f, 0.0f, 0.0f);
        }
        const int col = 1 + vc * 4;
        s[lr][col + 0] = v.x;
        s[lr][col + 1] = v.y;
        s[lr][col + 2] = v.z;
        s[lr][col + 3] = v.w;
    }

    // Per-channel coefficients (block-uniform; L2-cached broadcast)
    const float k0 = kern[c * 9 + 0];
    const float k1 = kern[c * 9 + 1];
    const float k2 = kern[c * 9 + 2];
    const float k3 = kern[c * 9 + 3];
    const float k4 = kern[c * 9 + 4];
    const float k5 = kern[c * 9 + 5];
    const float k6 = kern[c * 9 + 6];
    const float k7 = kern[c * 9 + 7];
    const float k8 = kern[c * 9 + 8];
    const float gwc = gw[c];
    const float gbc = gb[c];

    __syncthreads();

    // 16 rows x 128 cols = 2048 outputs, 8 per thread, coalesced stores.
    for (int i = tid; i < TILE_H * WW; i += 256) {
        const int r = i >> 7;     // output row within tile
        const int w = i & 127;    // output col

        const float center = s[r + 1][w + 1];
        const float t      = fmaf(center, gwc, gbc);
        const float theta  = 1.0f / (1.0f + __expf(-t));

        float m;
        m = fmaf(theta, k0, s[r + 0][w + 0]);
        m = fmaxf(m, fmaf(theta, k1, s[r + 0][w + 1]));
        m = fmaxf(m, fmaf(theta, k2, s[r + 0][w + 2]));
        m = fmaxf(m, fmaf(theta, k3, s[r + 1][w + 0]));
        m = fmaxf(m, fmaf(theta, k4, center));
        m = fmaxf(m, fmaf(theta, k5, s[r + 1][w + 2]));
        m = fmaxf(m, fmaf(theta, k6, s[r + 2][w + 0]));
        m = fmaxf(m, fmaf(theta, k7, s[r + 2][w + 1]));
        m = fmaxf(m, fmaf(theta, k8, s[r + 2][w + 2]));

        op[(h0 + r) * WW + w] = m;
    }
}

extern "C" void kernel_launch(void* const* d_in, const int* in_sizes, int n_in,
                              void* d_out, int out_size, void* d_ws, size_t ws_size,
                              hipStream_t stream) {
    const float* x    = (const float*)d_in[0];
    const float* kern = (const float*)d_in[1];
    const float* gw   = (const float*)d_in[2];
    const float* gb   = (const float*)d_in[3];
    float* out        = (float*)d_out;

    dim3 grid(HH / TILE_H, CC, BB);   // (8, 192, 8) = 12288 blocks
    dim3 block(256);
    dynmorph_kernel<<<grid, block, 0, stream>>>(x, kern, gw, gb, out);
}